// Round 10
// baseline (597.848 us; speedup 1.0000x reference)
//
#include <hip/hip_runtime.h>
#include <hip/hip_bf16.h>
#include <math.h>

#define K 4
#define F 513
#define B 4000
#define NIT 5
#define FB (F*B)
#define KB (K*B)
#define FCH 4         // f-chunk for demix
#define NFC 129       // ceil(513/4)
#define FCHF 8        // f-chunk for final
#define NFCF 65
#define VY 4          // B-split for v partials
#define VB (B/VY)     // 1000

// ---------------- persistent scratch: static device globals ------------------
__device__ float2 g_Wh[F*16];        // (F,4,4) complex fp32
__device__ float2 g_Vp[VY*64*F];     // partial V, (y, k*16+i*4+j, f)
__device__ float2 g_scale[F*4];      // (F,4) complex fp32
__device__ float  g_r2p[NFC*KB];     // per-chunk partials (plain stores)
__device__ float  g_r2[KB];          // reduced (K,B)

// ---------------- complex double helpers (tiny per-f solves only) -----------
struct cd { double re, im; };
__device__ inline cd mkcd(double r, double i){ cd z; z.re=r; z.im=i; return z; }
__device__ inline cd cmul(cd a, cd b){ return mkcd(a.re*b.re - a.im*b.im, a.re*b.im + a.im*b.re); }
__device__ inline cd cadd(cd a, cd b){ return mkcd(a.re+b.re, a.im+b.im); }
__device__ inline cd csub(cd a, cd b){ return mkcd(a.re-b.re, a.im-b.im); }
__device__ inline cd conj_(cd a){ return mkcd(a.re, -a.im); }
__device__ inline cd cdiv(cd a, cd b){
  double d = b.re*b.re + b.im*b.im;
  return mkcd((a.re*b.re + a.im*b.im)/d, (a.im*b.re - a.re*b.im)/d);
}

// x = inv(M)[:,kk] via cofactors (branch-free, no pivoting).
__device__ inline void invcol4(const cd M[4][4], int kk, cd x[4]){
  int r0 = (kk==0)?1:0;
  int r1 = (kk<=1)?2:1;
  int r2 = (kk<=2)?3:2;
  cd cof[4];
  #pragma unroll
  for (int i=0;i<4;++i){
    int c0 = (i==0)?1:0;
    int c1 = (i<=1)?2:1;
    int c2 = (i<=2)?3:2;
    cd m = cadd(csub(cmul(M[r0][c0], csub(cmul(M[r1][c1],M[r2][c2]), cmul(M[r1][c2],M[r2][c1]))),
                     cmul(M[r0][c1], csub(cmul(M[r1][c0],M[r2][c2]), cmul(M[r1][c2],M[r2][c0])))),
                cmul(M[r0][c2], csub(cmul(M[r1][c0],M[r2][c1]), cmul(M[r1][c1],M[r2][c0]))));
    if ((kk+i)&1) m = mkcd(-m.re,-m.im);
    cof[i] = m;
  }
  cd det = mkcd(0.0,0.0);
  #pragma unroll
  for (int i=0;i<4;++i) det = cadd(det, cmul(M[kk][i], cof[i]));
  cd idet = cdiv(mkcd(1.0,0.0), det);
  #pragma unroll
  for (int i=0;i<4;++i) x[i] = cmul(cof[i], idet);
}

// ---------------- kernels ---------------------------------------------------

__global__ void init_kernel(){
  int t = blockIdx.x*blockDim.x + threadIdx.x;
  if (t < F*16){
    int sc = t & 15; int s = sc >> 2, c = sc & 3;
    g_Wh[t] = make_float2(s==c ? 1.0f : 0.0f, 0.0f);
  }
}

// partial r2: r2p[y,k,b] = sum over f-chunk y of |(Wh[f] X[:,f,b])[k]|^2
__global__ __launch_bounds__(256) void demix_part_kernel(
    const float* __restrict__ Xr, const float* __restrict__ Xi){
  int b = blockIdx.x*blockDim.x + threadIdx.x;
  if (b >= B) return;
  int y = blockIdx.y;
  int f0 = y*FCH, f1 = min(f0+FCH, F);
  float acc[K];
  #pragma unroll
  for (int s=0;s<K;++s) acc[s]=0.0f;
  for (int f=f0; f<f1; ++f){
    float xr[K], xi[K];
    #pragma unroll
    for (int c=0;c<K;++c){ int idx=c*FB + f*B + b; xr[c]=Xr[idx]; xi[c]=Xi[idx]; }
    const float2* w = g_Wh + f*16;
    #pragma unroll
    for (int s=0;s<K;++s){
      float yr=0.0f, yi=0.0f;
      #pragma unroll
      for (int c=0;c<K;++c){
        float2 ww = w[s*4+c];
        yr += ww.x*xr[c] - ww.y*xi[c];
        yi += ww.x*xi[c] + ww.y*xr[c];
      }
      acc[s] += yr*yr + yi*yi;
    }
  }
  #pragma unroll
  for (int s=0;s<K;++s) g_r2p[y*KB + s*B + b] = acc[s];
}

// r2[k,b] = sum_y r2p[y,k,b]
__global__ __launch_bounds__(256) void reduce_r2_kernel(){
  int t = blockIdx.x*blockDim.x + threadIdx.x;
  if (t >= KB) return;
  float s = 0.0f;
  for (int y=0; y<NFC; ++y) s += g_r2p[y*KB + t];
  g_r2[t] = s;
}

// Partial V over B-chunk y: Vp[y,k,i,j,f] = (1/B) sum_{b in chunk} phi[k,b] X_i conj(X_j)
__global__ __launch_bounds__(256) void v_kernel(
    const float* __restrict__ Xr, const float* __restrict__ Xi){
  int f = blockIdx.x;
  int y = blockIdx.y;
  int tid = threadIdx.x;
  float acc[64];
  #pragma unroll
  for (int q=0;q<64;++q) acc[q]=0.0f;

  int b0 = y*VB, b1 = b0 + VB;
  for (int b=b0+tid; b<b1; b+=256){
    float phi[K];
    #pragma unroll
    for (int k=0;k<K;++k) phi[k] = 0.5f / sqrtf(g_r2[k*B+b]);
    float xr[K], xi[K];
    #pragma unroll
    for (int c=0;c<K;++c){ int idx=c*FB + f*B + b; xr[c]=Xr[idx]; xi[c]=Xi[idx]; }
    float p[16];
    #pragma unroll
    for (int i=0;i<4;++i) p[i] = xr[i]*xr[i] + xi[i]*xi[i];
    int s = 4;
    #pragma unroll
    for (int i=0;i<4;++i){
      #pragma unroll
      for (int j=i+1;j<4;++j){
        p[s++] = xr[i]*xr[j] + xi[i]*xi[j];
        p[s++] = xi[i]*xr[j] - xr[i]*xi[j];
      }
    }
    #pragma unroll
    for (int k=0;k<K;++k){
      #pragma unroll
      for (int q=0;q<16;++q) acc[k*16+q] += phi[k]*p[q];
    }
  }

  __shared__ float part[4*64];
  __shared__ float red[64];
  int lane = tid & 63, wave = tid >> 6;
  #pragma unroll
  for (int q=0;q<64;++q){
    float v = acc[q];
    for (int off=32; off>0; off>>=1) v += __shfl_down(v, off);
    if (lane == 0) part[wave*64+q] = v;
  }
  __syncthreads();
  if (tid < 64){
    red[tid] = (part[tid] + part[64+tid] + part[128+tid] + part[192+tid]) * (1.0f/B);
  }
  __syncthreads();
  if (tid < 64){
    int k = tid >> 4, ij = tid & 15, i = ij >> 2, j = ij & 3;
    float re, im;
    if (i == j){ re = red[k*16 + i]; im = 0.0f; }
    else {
      int a = min(i,j), c2 = max(i,j);
      int pidx = (a==0) ? (c2-1) : ((a==1) ? (c2+1) : 5);
      re = red[k*16 + 4 + 2*pidx];
      im = red[k*16 + 5 + 2*pidx];
      if (i > j) im = -im;
    }
    g_Vp[(y*64 + tid)*F + f] = make_float2(re, im);
  }
}

// Per-f IP updates k=0..3 (sequential), fp64 cofactor solves, branch-free.
__global__ __launch_bounds__(64) void update_kernel(int do_scale){
  int f = blockIdx.x*blockDim.x + threadIdx.x;
  if (f >= F) return;
  cd W[4][4];
  #pragma unroll
  for (int s=0;s<4;++s)
    #pragma unroll
    for (int c=0;c<4;++c){ float2 w = g_Wh[f*16+s*4+c]; W[s][c] = mkcd((double)w.x,(double)w.y); }

  #pragma unroll
  for (int k=0;k<4;++k){
    cd Vk[4][4];
    #pragma unroll
    for (int i=0;i<4;++i)
      #pragma unroll
      for (int j=0;j<4;++j){
        int q = (k*4+i)*4+j;
        float re=0.0f, im=0.0f;
        #pragma unroll
        for (int y=0;y<VY;++y){ float2 v = g_Vp[(y*64+q)*F + f]; re += v.x; im += v.y; }
        Vk[i][j] = mkcd((double)re,(double)im);
      }
    cd M[4][4];
    #pragma unroll
    for (int i=0;i<4;++i)
      #pragma unroll
      for (int j=0;j<4;++j){
        cd s = mkcd(0.0,0.0);
        #pragma unroll
        for (int c=0;c<4;++c) s = cadd(s, cmul(W[i][c], Vk[c][j]));
        M[i][j] = s;
      }
    cd x[4];
    invcol4(M, k, x);                  // x = inv(M)[:,k]
    cd w[4];
    #pragma unroll
    for (int c=0;c<4;++c) w[c] = conj_(x[c]);
    double dre = 0.0;
    #pragma unroll
    for (int j=0;j<4;++j){
      cd tj = mkcd(0.0,0.0);
      #pragma unroll
      for (int c=0;c<4;++c) tj = cadd(tj, cmul(w[c], Vk[c][j]));
      dre += tj.re*w[j].re + tj.im*w[j].im;   // Re(tj * conj(w_j))
    }
    double inv_denom = rsqrt(dre > 0.0 ? dre : 1e-300);
    #pragma unroll
    for (int c=0;c<4;++c) W[k][c] = mkcd(w[c].re*inv_denom, w[c].im*inv_denom);
  }
  #pragma unroll
  for (int s=0;s<4;++s)
    #pragma unroll
    for (int c=0;c<4;++c) g_Wh[f*16+s*4+c] = make_float2((float)W[s][c].re, (float)W[s][c].im);

  if (do_scale){
    cd x[4];
    invcol4(W, 0, x);   // x = inv(Wh)[:,0]
    #pragma unroll
    for (int s=0;s<4;++s) g_scale[f*4+s] = make_float2((float)x[s].re, (float)x[s].im);
  }
}

// out[s,f,b] = (Wh[f] X[:,f,b])[s] * scale[f,s]; interleaved (re,im) bf16 pairs
__global__ __launch_bounds__(256) void final_kernel(
    const float* __restrict__ Xr, const float* __restrict__ Xi,
    __hip_bfloat162* __restrict__ out){
  int b = blockIdx.x*blockDim.x + threadIdx.x;
  if (b >= B) return;
  int f0 = blockIdx.y*FCHF, f1 = min(f0+FCHF, F);
  for (int f=f0; f<f1; ++f){
    float xr[K], xi[K];
    #pragma unroll
    for (int c=0;c<K;++c){ int idx=c*FB + f*B + b; xr[c]=Xr[idx]; xi[c]=Xi[idx]; }
    const float2* w = g_Wh + f*16;
    #pragma unroll
    for (int s=0;s<K;++s){
      float yr=0.0f, yi=0.0f;
      #pragma unroll
      for (int c=0;c<K;++c){
        float2 ww = w[s*4+c];
        yr += ww.x*xr[c] - ww.y*xi[c];
        yi += ww.x*xi[c] + ww.y*xr[c];
      }
      float2 sc = g_scale[f*4+s];
      __hip_bfloat162 o;
      o.x = __float2bfloat16(yr*sc.x - yi*sc.y);
      o.y = __float2bfloat16(yr*sc.y + yi*sc.x);
      out[s*FB + f*B + b] = o;
    }
  }
}

// ---------------- launch ----------------------------------------------------
extern "C" void kernel_launch(void* const* d_in, const int* in_sizes, int n_in,
                              void* d_out, int out_size, void* d_ws, size_t ws_size,
                              hipStream_t stream){
  // Inputs arrive alphabetized: d_in[0]="Xi", d_in[1]="Xr" (verified round 7).
  const float* Xr = (const float*)d_in[1];
  const float* Xi = (const float*)d_in[0];
  __hip_bfloat162* out = (__hip_bfloat162*)d_out;

  init_kernel<<<33, 256, 0, stream>>>();
  dim3 gD((B + 255)/256, NFC);
  dim3 gV(F, VY);
  dim3 gF((B + 255)/256, NFCF);
  for (int it=0; it<NIT; ++it){
    demix_part_kernel<<<gD, 256, 0, stream>>>(Xr, Xi);
    reduce_r2_kernel<<<(KB + 255)/256, 256, 0, stream>>>();
    v_kernel<<<gV, 256, 0, stream>>>(Xr, Xi);
    update_kernel<<<(F + 63)/64, 64, 0, stream>>>(it == NIT-1 ? 1 : 0);
  }
  final_kernel<<<gF, 256, 0, stream>>>(Xr, Xi, out);
}

// Round 11
// 484.561 us; speedup vs baseline: 1.2338x; 1.2338x over previous
//
#include <hip/hip_runtime.h>
#include <hip/hip_bf16.h>
#include <math.h>

#define K 4
#define F 513
#define B 4000
#define NIT 5
#define FB (F*B)
#define KB (K*B)
#define BQ (B/4)      // 1000 quads
#define FBQ (FB/4)    // 513000
#define KBQ (KB/4)    // 4000
#define FCH 4         // f-chunk for demix
#define NFC 129       // ceil(513/4)
#define FCHF 4        // f-chunk for final
#define NFCF 129

// ---------------- persistent scratch: static device globals ------------------
__device__ float2 g_Wh[F*16];        // (F,4,4) complex fp32
__device__ float2 g_V[64*F];         // (k*16+i*4+j, f) complex fp32
__device__ float2 g_scale[F*4];      // (F,4) complex fp32
__device__ float  g_r2p[NFC*KB];     // per-chunk partials (plain stores)
__device__ float  g_phi[KB];         // phi[k,b] = 0.5/sqrt(r2)

// ---------------- float4 helpers --------------------------------------------
__device__ inline float4 f4_fma(float a, float4 x, float4 acc){
  return make_float4(fmaf(a,x.x,acc.x), fmaf(a,x.y,acc.y), fmaf(a,x.z,acc.z), fmaf(a,x.w,acc.w));
}
__device__ inline float4 f4_sqacc(float4 yr, float4 yi, float4 acc){
  return make_float4(fmaf(yr.x,yr.x,fmaf(yi.x,yi.x,acc.x)),
                     fmaf(yr.y,yr.y,fmaf(yi.y,yi.y,acc.y)),
                     fmaf(yr.z,yr.z,fmaf(yi.z,yi.z,acc.z)),
                     fmaf(yr.w,yr.w,fmaf(yi.w,yi.w,acc.w)));
}

// ---------------- complex double helpers (tiny per-f solves only) -----------
struct cd { double re, im; };
__device__ inline cd mkcd(double r, double i){ cd z; z.re=r; z.im=i; return z; }
__device__ inline cd cmul(cd a, cd b){ return mkcd(a.re*b.re - a.im*b.im, a.re*b.im + a.im*b.re); }
__device__ inline cd cadd(cd a, cd b){ return mkcd(a.re+b.re, a.im+b.im); }
__device__ inline cd csub(cd a, cd b){ return mkcd(a.re-b.re, a.im-b.im); }
__device__ inline cd conj_(cd a){ return mkcd(a.re, -a.im); }
__device__ inline cd cdiv(cd a, cd b){
  double d = b.re*b.re + b.im*b.im;
  return mkcd((a.re*b.re + a.im*b.im)/d, (a.im*b.re - a.re*b.im)/d);
}

// x = inv(M)[:,kk] via cofactors (branch-free, no pivoting).
__device__ inline void invcol4(const cd M[4][4], int kk, cd x[4]){
  int r0 = (kk==0)?1:0;
  int r1 = (kk<=1)?2:1;
  int r2 = (kk<=2)?3:2;
  cd cof[4];
  #pragma unroll
  for (int i=0;i<4;++i){
    int c0 = (i==0)?1:0;
    int c1 = (i<=1)?2:1;
    int c2 = (i<=2)?3:2;
    cd m = cadd(csub(cmul(M[r0][c0], csub(cmul(M[r1][c1],M[r2][c2]), cmul(M[r1][c2],M[r2][c1]))),
                     cmul(M[r0][c1], csub(cmul(M[r1][c0],M[r2][c2]), cmul(M[r1][c2],M[r2][c0])))),
                cmul(M[r0][c2], csub(cmul(M[r1][c0],M[r2][c1]), cmul(M[r1][c1],M[r2][c0]))));
    if ((kk+i)&1) m = mkcd(-m.re,-m.im);
    cof[i] = m;
  }
  cd det = mkcd(0.0,0.0);
  #pragma unroll
  for (int i=0;i<4;++i) det = cadd(det, cmul(M[kk][i], cof[i]));
  cd idet = cdiv(mkcd(1.0,0.0), det);
  #pragma unroll
  for (int i=0;i<4;++i) x[i] = cmul(cof[i], idet);
}

// ---------------- kernels ---------------------------------------------------

__global__ void init_kernel(){
  int t = blockIdx.x*blockDim.x + threadIdx.x;
  if (t < F*16){
    int sc = t & 15; int s = sc >> 2, c = sc & 3;
    g_Wh[t] = make_float2(s==c ? 1.0f : 0.0f, 0.0f);
  }
}

// partial r2: r2p[y,k,b] = sum over f-chunk y of |(Wh[f] X[:,f,b])[k]|^2 (float4 over b)
__global__ __launch_bounds__(256) void demix_part_kernel(
    const float* __restrict__ Xr, const float* __restrict__ Xi){
  int bq = blockIdx.x*blockDim.x + threadIdx.x;
  if (bq >= BQ) return;
  int y = blockIdx.y;
  int f0 = y*FCH, f1 = min(f0+FCH, F);
  const float4* Xr4 = (const float4*)Xr;
  const float4* Xi4 = (const float4*)Xi;
  float4 acc[K];
  #pragma unroll
  for (int s=0;s<K;++s) acc[s] = make_float4(0.f,0.f,0.f,0.f);
  for (int f=f0; f<f1; ++f){
    float4 xr4[K], xi4[K];
    #pragma unroll
    for (int c=0;c<K;++c){
      int idx = c*FBQ + f*BQ + bq;
      xr4[c] = Xr4[idx]; xi4[c] = Xi4[idx];
    }
    const float2* w = g_Wh + f*16;
    #pragma unroll
    for (int s=0;s<K;++s){
      float4 yr = make_float4(0.f,0.f,0.f,0.f), yi = yr;
      #pragma unroll
      for (int c=0;c<K;++c){
        float2 ww = w[s*4+c];
        yr = f4_fma(ww.x, xr4[c], yr); yr = f4_fma(-ww.y, xi4[c], yr);
        yi = f4_fma(ww.x, xi4[c], yi); yi = f4_fma( ww.y, xr4[c], yi);
      }
      acc[s] = f4_sqacc(yr, yi, acc[s]);
    }
  }
  float4* r2p4 = (float4*)g_r2p;
  #pragma unroll
  for (int s=0;s<K;++s) r2p4[y*KBQ + s*BQ + bq] = acc[s];
}

// phi[k,b] = 0.5 / sqrt( sum_y r2p[y,k,b] )
__global__ __launch_bounds__(256) void reduce_phi_kernel(){
  int t = blockIdx.x*blockDim.x + threadIdx.x;
  if (t >= KB) return;
  float s = 0.0f;
  for (int y=0; y<NFC; ++y) s += g_r2p[y*KB + t];
  g_phi[t] = 0.5f / sqrtf(s);
}

// V[k,i,j,f] = (1/B) sum_b phi[k,b] X[i,f,b] conj(X[j,f,b]); one block per f, float4 over b.
__global__ __launch_bounds__(256) void v_kernel(
    const float* __restrict__ Xr, const float* __restrict__ Xi){
  int f = blockIdx.x;
  int tid = threadIdx.x;
  const float4* Xr4 = (const float4*)Xr;
  const float4* Xi4 = (const float4*)Xi;
  const float4* Phi4 = (const float4*)g_phi;
  float acc[64];
  #pragma unroll
  for (int q=0;q<64;++q) acc[q]=0.0f;

#define VSTEP(CP) do { \
    float a0=xr4[0].CP, a1=xr4[1].CP, a2=xr4[2].CP, a3=xr4[3].CP; \
    float b0=xi4[0].CP, b1=xi4[1].CP, b2=xi4[2].CP, b3=xi4[3].CP; \
    float p[16]; \
    p[0]=a0*a0+b0*b0; p[1]=a1*a1+b1*b1; p[2]=a2*a2+b2*b2; p[3]=a3*a3+b3*b3; \
    p[4]=a0*a1+b0*b1;  p[5]=b0*a1-a0*b1; \
    p[6]=a0*a2+b0*b2;  p[7]=b0*a2-a0*b2; \
    p[8]=a0*a3+b0*b3;  p[9]=b0*a3-a0*b3; \
    p[10]=a1*a2+b1*b2; p[11]=b1*a2-a1*b2; \
    p[12]=a1*a3+b1*b3; p[13]=b1*a3-a1*b3; \
    p[14]=a2*a3+b2*b3; p[15]=b2*a3-a2*b3; \
    float h0=phi4[0].CP, h1=phi4[1].CP, h2=phi4[2].CP, h3=phi4[3].CP; \
    _Pragma("unroll") \
    for (int q=0;q<16;++q){ \
      acc[q]    = fmaf(h0, p[q], acc[q]); \
      acc[16+q] = fmaf(h1, p[q], acc[16+q]); \
      acc[32+q] = fmaf(h2, p[q], acc[32+q]); \
      acc[48+q] = fmaf(h3, p[q], acc[48+q]); \
    } \
  } while(0)

  for (int bq=tid; bq<BQ; bq+=256){
    float4 xr4[K], xi4[K], phi4[K];
    #pragma unroll
    for (int c=0;c<K;++c){
      int idx = c*FBQ + f*BQ + bq;
      xr4[c] = Xr4[idx]; xi4[c] = Xi4[idx];
      phi4[c] = Phi4[c*BQ + bq];
    }
    VSTEP(x); VSTEP(y); VSTEP(z); VSTEP(w);
  }
#undef VSTEP

  __shared__ float part[4*64];
  __shared__ float red[64];
  int lane = tid & 63, wave = tid >> 6;
  #pragma unroll
  for (int q=0;q<64;++q){
    float v = acc[q];
    for (int off=32; off>0; off>>=1) v += __shfl_down(v, off);
    if (lane == 0) part[wave*64+q] = v;
  }
  __syncthreads();
  if (tid < 64){
    red[tid] = (part[tid] + part[64+tid] + part[128+tid] + part[192+tid]) * (1.0f/B);
  }
  __syncthreads();
  if (tid < 64){
    int k = tid >> 4, ij = tid & 15, i = ij >> 2, j = ij & 3;
    float re, im;
    if (i == j){ re = red[k*16 + i]; im = 0.0f; }
    else {
      int a = min(i,j), c2 = max(i,j);
      int pidx = (a==0) ? (c2-1) : ((a==1) ? (c2+1) : 5);
      re = red[k*16 + 4 + 2*pidx];
      im = red[k*16 + 5 + 2*pidx];
      if (i > j) im = -im;
    }
    g_V[(unsigned)tid*F + f] = make_float2(re, im);
  }
}

// Per-f IP updates k=0..3 (sequential), fp64 cofactor solves, branch-free.
__global__ __launch_bounds__(64) void update_kernel(int do_scale){
  int f = blockIdx.x*blockDim.x + threadIdx.x;
  if (f >= F) return;
  cd W[4][4];
  #pragma unroll
  for (int s=0;s<4;++s)
    #pragma unroll
    for (int c=0;c<4;++c){ float2 w = g_Wh[f*16+s*4+c]; W[s][c] = mkcd((double)w.x,(double)w.y); }

  #pragma unroll
  for (int k=0;k<4;++k){
    cd Vk[4][4];
    #pragma unroll
    for (int i=0;i<4;++i)
      #pragma unroll
      for (int j=0;j<4;++j){ float2 v = g_V[((k*4+i)*4+j)*F + f]; Vk[i][j] = mkcd((double)v.x,(double)v.y); }
    cd M[4][4];
    #pragma unroll
    for (int i=0;i<4;++i)
      #pragma unroll
      for (int j=0;j<4;++j){
        cd s = mkcd(0.0,0.0);
        #pragma unroll
        for (int c=0;c<4;++c) s = cadd(s, cmul(W[i][c], Vk[c][j]));
        M[i][j] = s;
      }
    cd x[4];
    invcol4(M, k, x);                  // x = inv(M)[:,k]
    cd w[4];
    #pragma unroll
    for (int c=0;c<4;++c) w[c] = conj_(x[c]);
    double dre = 0.0;
    #pragma unroll
    for (int j=0;j<4;++j){
      cd tj = mkcd(0.0,0.0);
      #pragma unroll
      for (int c=0;c<4;++c) tj = cadd(tj, cmul(w[c], Vk[c][j]));
      dre += tj.re*w[j].re + tj.im*w[j].im;   // Re(tj * conj(w_j))
    }
    double inv_denom = rsqrt(dre > 0.0 ? dre : 1e-300);
    #pragma unroll
    for (int c=0;c<4;++c) W[k][c] = mkcd(w[c].re*inv_denom, w[c].im*inv_denom);
  }
  #pragma unroll
  for (int s=0;s<4;++s)
    #pragma unroll
    for (int c=0;c<4;++c) g_Wh[f*16+s*4+c] = make_float2((float)W[s][c].re, (float)W[s][c].im);

  if (do_scale){
    cd x[4];
    invcol4(W, 0, x);   // x = inv(Wh)[:,0]
    #pragma unroll
    for (int s=0;s<4;++s) g_scale[f*4+s] = make_float2((float)x[s].re, (float)x[s].im);
  }
}

// out[s,f,b] = (Wh[f] X[:,f,b])[s] * scale[f,s]; 16B packed bf16 (re,im)x4 stores
__global__ __launch_bounds__(256) void final_kernel(
    const float* __restrict__ Xr, const float* __restrict__ Xi,
    uint4* __restrict__ out){
  int bq = blockIdx.x*blockDim.x + threadIdx.x;
  if (bq >= BQ) return;
  int f0 = blockIdx.y*FCHF, f1 = min(f0+FCHF, F);
  const float4* Xr4 = (const float4*)Xr;
  const float4* Xi4 = (const float4*)Xi;
  for (int f=f0; f<f1; ++f){
    float4 xr4[K], xi4[K];
    #pragma unroll
    for (int c=0;c<K;++c){
      int idx = c*FBQ + f*BQ + bq;
      xr4[c] = Xr4[idx]; xi4[c] = Xi4[idx];
    }
    const float2* w = g_Wh + f*16;
    #pragma unroll
    for (int s=0;s<K;++s){
      float4 yr = make_float4(0.f,0.f,0.f,0.f), yi = yr;
      #pragma unroll
      for (int c=0;c<K;++c){
        float2 ww = w[s*4+c];
        yr = f4_fma(ww.x, xr4[c], yr); yr = f4_fma(-ww.y, xi4[c], yr);
        yi = f4_fma(ww.x, xi4[c], yi); yi = f4_fma( ww.y, xr4[c], yi);
      }
      float2 sc = g_scale[f*4+s];
      union { uint4 v; __hip_bfloat162 h[4]; } pk;
      pk.h[0] = __hip_bfloat162{__float2bfloat16(yr.x*sc.x - yi.x*sc.y), __float2bfloat16(yr.x*sc.y + yi.x*sc.x)};
      pk.h[1] = __hip_bfloat162{__float2bfloat16(yr.y*sc.x - yi.y*sc.y), __float2bfloat16(yr.y*sc.y + yi.y*sc.x)};
      pk.h[2] = __hip_bfloat162{__float2bfloat16(yr.z*sc.x - yi.z*sc.y), __float2bfloat16(yr.z*sc.y + yi.z*sc.x)};
      pk.h[3] = __hip_bfloat162{__float2bfloat16(yr.w*sc.x - yi.w*sc.y), __float2bfloat16(yr.w*sc.y + yi.w*sc.x)};
      out[s*FBQ + f*BQ + bq] = pk.v;
    }
  }
}

// ---------------- launch ----------------------------------------------------
extern "C" void kernel_launch(void* const* d_in, const int* in_sizes, int n_in,
                              void* d_out, int out_size, void* d_ws, size_t ws_size,
                              hipStream_t stream){
  // Inputs arrive alphabetized: d_in[0]="Xi", d_in[1]="Xr" (verified round 7).
  const float* Xr = (const float*)d_in[1];
  const float* Xi = (const float*)d_in[0];
  uint4* out = (uint4*)d_out;

  init_kernel<<<33, 256, 0, stream>>>();
  dim3 gD((BQ + 255)/256, NFC);
  dim3 gF((BQ + 255)/256, NFCF);
  for (int it=0; it<NIT; ++it){
    demix_part_kernel<<<gD, 256, 0, stream>>>(Xr, Xi);
    reduce_phi_kernel<<<(KB + 255)/256, 256, 0, stream>>>();
    v_kernel<<<F, 256, 0, stream>>>(Xr, Xi);
    update_kernel<<<(F + 63)/64, 64, 0, stream>>>(it == NIT-1 ? 1 : 0);
  }
  final_kernel<<<gF, 256, 0, stream>>>(Xr, Xi, out);
}